// Round 5
// baseline (437.744 us; speedup 1.0000x reference)
//
#include <hip/hip_runtime.h>
#include <hip/hip_bf16.h>

// Problem constants (from reference)
#define NN 50000
#define EE 1600000
#define DIN 128

#define BKT_SHIFT 6                       // 64 nodes per bucket
#define NB ((NN + 63) >> 6)               // 782 buckets
#define BSLACK 2688                       // slack slots per bucket (mean 2110, +12.5 sigma)
#define CHUNK 4096                        // edges per binning workgroup (16/thread)
#define ZOUT (NN * 16 / 4)                // float4 slots to zero in d_out

typedef _Float16 half_t;
typedef __attribute__((ext_vector_type(2))) _Float16 half2_t;
typedef __attribute__((ext_vector_type(4))) _Float16 half4_t;
typedef __attribute__((ext_vector_type(8))) _Float16 half8_t;
typedef __attribute__((ext_vector_type(4))) float float4_t;

// v_fma_mix_f32: acc(f32) += x(f32) * f16half(t). Kills the separate
// v_cvt_f32_f16 per gathered feature (half the inner-loop VALU).
#define FMIX_LO(a, x, t) \
    asm("v_fma_mix_f32 %0, %1, %2, %0 op_sel:[0,0,0] op_sel_hi:[0,1,0]" \
        : "+v"(a) : "v"(x), "v"(t))
#define FMIX_HI(a, x, t) \
    asm("v_fma_mix_f32 %0, %1, %2, %0 op_sel:[0,1,0] op_sel_hi:[0,1,0]" \
        : "+v"(a) : "v"(x), "v"(t))

__device__ __forceinline__ void mix_acc8(float* acc, float x, const unsigned int* t) {
#pragma unroll
    for (int r = 0; r < 4; ++r) {
        FMIX_LO(acc[2 * r], x, t[r]);
        FMIX_HI(acc[2 * r + 1], x, t[r]);
    }
}

// ---------------------------------------------------------------------------
// prep: build extended B^T hi/lo for each layer (W^T plus a 16-wide folded
// score tile: cols j<8 = ss head j, j>=8 = ds head j-8), zero gcursor, and
// zero d_out (layer-3 half blocks atomically accumulate into it).
// ---------------------------------------------------------------------------
__device__ __forceinline__ void split_write(half_t* __restrict__ bh, half_t* __restrict__ bl,
                                            int idx, float v) {
    half_t h = (half_t)v;
    bh[idx] = h;
    bl[idx] = (half_t)(v - (float)h);
}

__device__ __forceinline__ void build_bt(const float* __restrict__ W,
                                         const float* __restrict__ as,
                                         const float* __restrict__ ad,
                                         half_t* __restrict__ Bh, half_t* __restrict__ Bl,
                                         int elem, int NCOL, int H) {
    int r = elem >> 7, k = elem & 127;  // Bt row r (out col / score), k in 0..127
    float v;
    if (r < NCOL) {
        v = W[k * NCOL + r];
    } else {
        int j = r - NCOL;
        v = 0.f;
        if (j < 8) {
            if (j < H) {
                float s = 0.f;
#pragma unroll
                for (int f = 0; f < 16; ++f) s += W[k * NCOL + j * 16 + f] * as[j * 16 + f];
                v = s;
            }
        } else {
            int hh = j - 8;
            if (hh < H) {
                float s = 0.f;
#pragma unroll
                for (int f = 0; f < 16; ++f) s += W[k * NCOL + hh * 16 + f] * ad[hh * 16 + f];
                v = s;
            }
        }
    }
    split_write(Bh, Bl, r * 128 + k, v);
}

#define T1 (144 * 128)
#define T3 (80 * 128)
__global__ __launch_bounds__(256) void prep_kernel(
    const float* __restrict__ W1, const float* __restrict__ W2, const float* __restrict__ W3,
    const float* __restrict__ as1, const float* __restrict__ ad1,
    const float* __restrict__ as2, const float* __restrict__ ad2,
    const float* __restrict__ as3, const float* __restrict__ ad3,
    half_t* __restrict__ B1h, half_t* __restrict__ B1l,
    half_t* __restrict__ B2h, half_t* __restrict__ B2l,
    half_t* __restrict__ B3h, half_t* __restrict__ B3l,
    int* __restrict__ gcursor, float* __restrict__ dout) {
    int id = blockIdx.x * 256 + threadIdx.x;
    if (id < T1) {
        build_bt(W1, as1, ad1, B1h, B1l, id, 128, 8);
    } else if (id < 2 * T1) {
        build_bt(W2, as2, ad2, B2h, B2l, id - T1, 128, 8);
    } else if (id < 2 * T1 + T3) {
        build_bt(W3, as3, ad3, B3h, B3l, id - 2 * T1, 64, 4);
    } else {
        int i = id - (2 * T1 + T3);
        if (i < NB) {
            gcursor[i] = 0;
        } else {
            int z = i - NB;
            if (z < ZOUT) ((float4*)dout)[z] = make_float4(0.f, 0.f, 0.f, 0.f);
        }
    }
}

// ---------------------------------------------------------------------------
// CSR build (r9-proven): bucket binning -> per-bucket fine scatter into
// bucket-slack-layout csr with per-node begin/end. Packed src*64+dloc.
// ---------------------------------------------------------------------------
__global__ __launch_bounds__(256) void bin_kernel(const int* __restrict__ A,
                                                  int* __restrict__ gcursor,
                                                  int* __restrict__ binned, int e, int n) {
    __shared__ int lcount[NB];
    __shared__ int lbase[NB];
    int chunk0 = blockIdx.x * CHUNK;
    int cend = chunk0 + CHUNK;
    if (cend > e + n) cend = e + n;
    for (int i = threadIdx.x; i < NB; i += 256) lcount[i] = 0;
    __syncthreads();
    int sreg[16], dreg[16];
#pragma unroll
    for (int l = 0; l < 16; ++l) {
        int i = chunk0 + l * 256 + threadIdx.x;
        if (i < cend) {
            if (i < e) { sreg[l] = A[i]; dreg[l] = A[e + i]; }
            else       { sreg[l] = dreg[l] = i - e; }
            atomicAdd(&lcount[dreg[l] >> BKT_SHIFT], 1);
        } else {
            dreg[l] = -1;
        }
    }
    __syncthreads();
    for (int b = threadIdx.x; b < NB; b += 256) {
        int c = lcount[b];
        lbase[b] = c ? atomicAdd(&gcursor[b], c) : 0;
        lcount[b] = 0;
    }
    __syncthreads();
#pragma unroll
    for (int l = 0; l < 16; ++l) {
        if (dreg[l] >= 0) {
            int bkt = dreg[l] >> BKT_SHIFT;
            int pos = lbase[bkt] + atomicAdd(&lcount[bkt], 1);
            if (pos < BSLACK)
                binned[(size_t)bkt * BSLACK + pos] = (sreg[l] << 6) | (dreg[l] & 63);
        }
    }
}

__global__ __launch_bounds__(256) void fine_scatter(const int* __restrict__ binned,
                                                    const int* __restrict__ gcursor,
                                                    int* __restrict__ begE,
                                                    int* __restrict__ endE,
                                                    int* __restrict__ csr) {
    __shared__ int lc[64];
    __shared__ int scur[64];
    int b = blockIdx.x;
    int node0 = b << BKT_SHIFT;
    int cnt = gcursor[b];
    if (cnt > BSLACK) cnt = BSLACK;
    const int* bp = binned + (size_t)b * BSLACK;
    if (threadIdx.x < 64) lc[threadIdx.x] = 0;
    __syncthreads();
    for (int j = threadIdx.x; j < cnt; j += 256) atomicAdd(&lc[bp[j] & 63], 1);
    __syncthreads();
    if (threadIdx.x < 64) {  // wave-parallel exclusive scan over 64 counts
        int lane = threadIdx.x;
        int c = lc[lane];
        int v = c;
#pragma unroll
        for (int off = 1; off < 64; off <<= 1) {
            int u = __shfl_up(v, off, 64);
            if (lane >= off) v += u;
        }
        int begin = b * BSLACK + v - c;  // bucket-local slack layout
        scur[lane] = begin;
        int node = node0 + lane;
        if (node < NN) {
            begE[node] = begin;
            endE[node] = begin + c;
        }
    }
    __syncthreads();
    for (int j = threadIdx.x; j < cnt; j += 256) {
        int v = bp[j];
        int pos = atomicAdd(&scur[v & 63], 1);
        csr[pos] = v >> 6;
    }
}

// ---------------------------------------------------------------------------
// Split-fp16 MFMA GEMM, LDS-staged B in fragment order (proven main loop).
// Epilogue writes HALF-MAJOR outputs for the XCD-split aggregation:
//   C16[half][node][NCOL/2]   (64-feat halves -> 128 B rows, 2 full lines)
//   ss/ds[half][node][H/2]    scores pre-scaled by log2(e) for exp2f
// ---------------------------------------------------------------------------
template <int NTC, int H, bool A32>
__global__ __launch_bounds__(256) void gemm_mfma(
    const float* __restrict__ X32,
    const half_t* __restrict__ Ah, const half_t* __restrict__ Al,
    const half_t* __restrict__ Bth, const half_t* __restrict__ Btl,
    half_t* __restrict__ C16, float* __restrict__ ss, float* __restrict__ ds, int M) {
    constexpr int NCOL = NTC * 16;
    constexpr int NR = NTC + 1;               // tiles incl. score tile
    constexpr int NCHUNK = NR * 256;          // 16B chunks per B array
    constexpr int HH = H / 2;                 // heads per half
    __shared__ __align__(16) half_t Bs[2][NR * 2048];  // 73.7 KB (NTC=8)
    int tid = threadIdx.x;
    int w = tid >> 6, lane = tid & 63;
    int m = lane & 15, q = lane >> 4;
    int row0 = blockIdx.x * 64 + w * 16;

    // cooperative fragment-ordered B load (each thread NR chunks per array)
    for (int P = tid; P < NCHUNK; P += 256) {
        int nt = P >> 8, k0 = (P >> 6) & 3, qq = (P >> 4) & 3, mm = P & 15;
        int src = (nt * 16 + mm) * 128 + qq * 8 + k0 * 32;  // half index
        *(half8_t*)&Bs[0][(size_t)P * 8] = *(const half8_t*)&Bth[src];
        *(half8_t*)&Bs[1][(size_t)P * 8] = *(const half8_t*)&Btl[src];
    }

    // A fragment (VMEM, per-wave) — overlaps the barrier
    int ar = row0 + m;
    if (ar >= M) ar = M - 1;  // clamp (stores are guarded)
    half8_t ahf[4], alf[4];
    if constexpr (A32) {
        const float* px = X32 + (size_t)ar * 128 + q * 8;
#pragma unroll
        for (int k0 = 0; k0 < 4; ++k0) {
            float4 u0 = *(const float4*)(px + k0 * 32);
            float4 u1 = *(const float4*)(px + k0 * 32 + 4);
            float uv[8] = {u0.x, u0.y, u0.z, u0.w, u1.x, u1.y, u1.z, u1.w};
#pragma unroll
            for (int j = 0; j < 8; ++j) {
                half_t h = (half_t)uv[j];
                ahf[k0][j] = h;
                alf[k0][j] = (half_t)(uv[j] - (float)h);
            }
        }
    } else {
        const half_t* pa = Ah + (size_t)ar * 128 + q * 8;
        const half_t* pl = Al + (size_t)ar * 128 + q * 8;
#pragma unroll
        for (int k0 = 0; k0 < 4; ++k0) {
            ahf[k0] = *(const half8_t*)(pa + k0 * 32);
            alf[k0] = *(const half8_t*)(pl + k0 * 32);
        }
    }

    __syncthreads();

    float4_t acc[NR];
#pragma unroll
    for (int nt = 0; nt < NR; ++nt) {
        acc[nt][0] = 0.f; acc[nt][1] = 0.f; acc[nt][2] = 0.f; acc[nt][3] = 0.f;
    }

#pragma unroll
    for (int nt = 0; nt < NR; ++nt) {
#pragma unroll
        for (int k0 = 0; k0 < 4; ++k0) {
            half8_t bh = *(const half8_t*)&Bs[0][(size_t)((nt * 4 + k0) * 64 + lane) * 8];
            half8_t bl = *(const half8_t*)&Bs[1][(size_t)((nt * 4 + k0) * 64 + lane) * 8];
            acc[nt] = __builtin_amdgcn_mfma_f32_16x16x32_f16(ahf[k0], bh, acc[nt], 0, 0, 0);
            acc[nt] = __builtin_amdgcn_mfma_f32_16x16x32_f16(ahf[k0], bl, acc[nt], 0, 0, 0);
            acc[nt] = __builtin_amdgcn_mfma_f32_16x16x32_f16(alf[k0], bh, acc[nt], 0, 0, 0);
        }
    }

    // ss/ds half-major, pre-scaled by log2(e) (leaky-relu is positive-
    // homogeneous, so scaling commutes; aggregate uses exp2f).
#pragma unroll
    for (int r = 0; r < 4; ++r) {
        int grow = row0 + q * 4 + r;
        if (grow < M) {
            float v = acc[NTC][r] * 1.44269504f;
            if (m < H) {
                ss[((size_t)(m / HH) * M + grow) * HH + (m % HH)] = v;
            } else if (m >= 8 && m < 8 + H) {
                int mh = m - 8;
                ds[((size_t)(mh / HH) * M + grow) * HH + (mh % HH)] = v;
            }
        }
    }

    // C16 half-major store: reuse the B LDS region as transpose bounce
    __syncthreads();
    half_t* cs = (half_t*)Bs;  // [4][16][NCOL] strips, per-wave disjoint
#pragma unroll
    for (int nt = 0; nt < NTC; ++nt)
#pragma unroll
        for (int r = 0; r < 4; ++r)
            cs[(size_t)(w * 16 + q * 4 + r) * NCOL + nt * 16 + m] = (half_t)acc[nt][r];
    constexpr int LPR = NCOL / 8;   // lanes per row (16-B chunks)
    constexpr int RPP = 64 / LPR;   // rows per pass
    constexpr int NP = 16 / RPP;    // passes
    constexpr int HALFC = NCOL / 2;
    int rid = lane / LPR, cid = lane % LPR;
    int hsel = cid / (LPR / 2), lc = cid % (LPR / 2);
#pragma unroll
    for (int p = 0; p < NP; ++p) {
        int r = p * RPP + rid;
        int grow = row0 + r;
        half8_t v = *(const half8_t*)&cs[(size_t)(w * 16 + r) * NCOL + cid * 8];
        if (grow < M)
            *(half8_t*)(C16 + (size_t)hsel * M * HALFC + (size_t)grow * HALFC + lc * 8) = v;
    }
}

// ---------------------------------------------------------------------------
// XCD-pinned head-half aggregation. blockIdx&7 selects XCD (empirical
// round-robin mapping); XCDs 0-3 process half 0, XCDs 4-7 half 1 -> each
// XCD's gather table is 6.4 MB (vs 12.8), near-L2-resident, FULL-LINE
// requests preserved: per edge one 128 B contiguous row read by 8 lanes.
// Per-edge lane-work is split-neutral: 8 lanes x 2 halves = old 16 lanes.
// Layers 1-2 (!MEAN): hi/lo fp16 outputs node-major [node][128].
// Layer 3 (MEAN, H=4): halves of 2 heads, 64 B rows, 4 lanes/edge; the two
// half blocks atomically add per-head-normalized quarters into zeroed d_out.
// ---------------------------------------------------------------------------
template <int H, bool MEAN, bool RELU>
__global__ __launch_bounds__(256) void aggregate_oc(
    const half_t* __restrict__ h, const float* __restrict__ ss, const float* __restrict__ dsa,
    const int* __restrict__ csr, const int* __restrict__ begE, const int* __restrict__ endE,
    const float* __restrict__ bias, half_t* __restrict__ outh, half_t* __restrict__ outl,
    float* __restrict__ out, int n, int groups) {
    constexpr int HH = H / 2;       // heads per half (4 or 2)
    constexpr int FH = HH * 16;     // feats per half (64 or 32)
    constexpr int LPE = FH / 8;     // lanes per edge (8 or 4)
    constexpr int SPW = 64 / LPE;   // edge streams per wave (8 or 16)
    int b = blockIdx.x;
    int xcd = b & 7;
    int half = xcd >> 2;
    int g = (b >> 3) * 4 + (xcd & 3);
    if (g >= groups) return;
    int node = g * 4 + (int)(threadIdx.x >> 6);
    if (node >= n) return;
    int lane = threadIdx.x & 63;
    int o = lane / LPE, l = lane % LPE;
    int head = l >> 1;              // head within half (16 feats/head, 2 lanes)
    const float* sshp = ss + (size_t)half * n * HH + head;
    const half_t* hp = h + (size_t)half * n * FH + l * 8;
    float dsc = dsa[((size_t)half * n + node) * HH + head];
    int begin = begE[node], end = endE[node];

    float ssum = 0.f;
    float acc[8];
#pragma unroll
    for (int k = 0; k < 8; ++k) acc[k] = 0.f;

    int j = begin + o;              // this stream's edges: j, j+SPW, ...
    for (; j + 3 * SPW < end; j += 4 * SPW) {  // 4 edges, loads up front
        int s[4];
#pragma unroll
        for (int u = 0; u < 4; ++u) s[u] = csr[j + SPW * u];
        float e[4];
        unsigned int t[4][4];
#pragma unroll
        for (int u = 0; u < 4; ++u) {
            e[u] = sshp[(size_t)s[u] * HH];
            uint4 v = *(const uint4*)(hp + (size_t)s[u] * FH);
            t[u][0] = v.x; t[u][1] = v.y; t[u][2] = v.z; t[u][3] = v.w;
        }
#pragma unroll
        for (int u = 0; u < 4; ++u) {
            float ev = e[u] + dsc;
            ev = fmaxf(ev, 0.2f * ev);
            float x = exp2f(ev);
            ssum += x;
            mix_acc8(acc, x, t[u]);
        }
    }
    for (; j < end; j += SPW) {     // singles: at most 3 per stream
        int s0 = csr[j];
        float ev = sshp[(size_t)s0 * HH] + dsc;
        uint4 v = *(const uint4*)(hp + (size_t)s0 * FH);
        unsigned int t[4] = {v.x, v.y, v.z, v.w};
        ev = fmaxf(ev, 0.2f * ev);
        float x = exp2f(ev);
        ssum += x;
        mix_acc8(acc, x, t);
    }

    // reduce across the SPW streams (lanes with equal l share features)
#pragma unroll
    for (int off = LPE; off < 64; off <<= 1) {
        ssum += __shfl_xor(ssum, off, 64);
#pragma unroll
        for (int k = 0; k < 8; ++k) acc[k] += __shfl_xor(acc[k], off, 64);
    }
    float inv = 1.f / (ssum + 1e-16f);

    if constexpr (!MEAN) {
        if (lane < LPE) {           // LPE lanes x 16 B: one 128 B run per half
            half8_t hv, lv;
#pragma unroll
            for (int k = 0; k < 8; ++k) {
                float t = acc[k] * inv + bias[half * FH + l * 8 + k];
                if (RELU) t = fmaxf(t, 0.f);
                hv[k] = (half_t)t;
                lv[k] = (half_t)(t - (float)hv[k]);
            }
            size_t off = (size_t)node * (2 * FH) + half * FH + l * 8;
            *(half8_t*)(outh + off) = hv;
            *(half8_t*)(outl + off) = lv;
        }
    } else {
        // HH==2: per-head normalize, sum the half's 2 heads, atomic into
        // d_out (x0.25 for 4-head mean; bias*0.5 added by both halves).
        float v[8];
#pragma unroll
        for (int k = 0; k < 8; ++k) {
            float t = acc[k] * inv;
            t += __shfl_xor(t, 2, 64);  // add the other head of this half
            v[k] = t * 0.25f + bias[(l & 1) * 8 + k] * 0.5f;
        }
        if (lane < 2) {
#pragma unroll
            for (int k = 0; k < 8; ++k)
                atomicAdd(out + (size_t)node * 16 + l * 8 + k, v[k]);
        }
    }
}

// ---------------------------------------------------------------------------
extern "C" void kernel_launch(void* const* d_in, const int* in_sizes, int n_in,
                              void* d_out, int out_size, void* d_ws, size_t ws_size,
                              hipStream_t stream) {
    const float* X  = (const float*)d_in[0];
    const int*   A  = (const int*)d_in[1];
    const float* W1 = (const float*)d_in[2];
    const float* as1 = (const float*)d_in[3];
    const float* ad1 = (const float*)d_in[4];
    const float* b1  = (const float*)d_in[5];
    const float* W2 = (const float*)d_in[6];
    const float* as2 = (const float*)d_in[7];
    const float* ad2 = (const float*)d_in[8];
    const float* b2  = (const float*)d_in[9];
    const float* W3 = (const float*)d_in[10];
    const float* as3 = (const float*)d_in[11];
    const float* ad3 = (const float*)d_in[12];
    const float* b3  = (const float*)d_in[13];

    const int N = NN, E = EE;
    const int Etot = E + N;

    char* p = (char*)d_ws;
    auto take = [&](size_t bytes) {
        char* r = p;
        p += (bytes + 255) & ~(size_t)255;
        return (void*)r;
    };
    half_t* C16   = (half_t*)take((size_t)N * 128 * 2);  // half-major h tables
    half_t* Ph    = (half_t*)take((size_t)N * 128 * 2);  // layer-1/2 activations hi
    half_t* Pl    = (half_t*)take((size_t)N * 128 * 2);  // layer-1/2 activations lo
    float* ssb    = (float*)take((size_t)N * 8 * 4);     // half-major [2][N][H/2]
    float* dsb    = (float*)take((size_t)N * 8 * 4);     // half-major [2][N][H/2]
    int* begE     = (int*)take((size_t)N * 4);
    int* endE     = (int*)take((size_t)N * 4);
    int* gcursor  = (int*)take((size_t)NB * 4);
    int* csr      = (int*)take((size_t)NB * BSLACK * 4); // slack layout, 8.4 MB
    half_t* B1h   = (half_t*)take(144 * 128 * 2);
    half_t* B1l   = (half_t*)take(144 * 128 * 2);
    half_t* B2h   = (half_t*)take(144 * 128 * 2);
    half_t* B2l   = (half_t*)take(144 * 128 * 2);
    half_t* B3h   = (half_t*)take(80 * 128 * 2);
    half_t* B3l   = (half_t*)take(80 * 128 * 2);
    // binned slack regions alias Ph (8.4 MB < 12.8 MB); Ph is dead until the
    // layer-1 aggregate, which runs strictly after fine_scatter.
    int* binned   = (int*)Ph;

    // --- prep (W^T hi/lo + folded score cols, gcursor zero, d_out zero) ---
    const int prepTotal = 2 * T1 + T3 + NB + ZOUT;
    prep_kernel<<<(prepTotal + 255) / 256, 256, 0, stream>>>(
        W1, W2, W3, as1, ad1, as2, ad2, as3, ad3,
        B1h, B1l, B2h, B2l, B3h, B3l, gcursor, (float*)d_out);
    bin_kernel<<<(Etot + CHUNK - 1) / CHUNK, 256, 0, stream>>>(A, gcursor, binned, E, N);
    fine_scatter<<<NB, 256, 0, stream>>>(binned, gcursor, begE, endE, csr);

    const int gemmRows = (N + 63) / 64;
    const int aggBlocks = (N + 3) / 4;                  // 12500 groups of 4 nodes
    const int gridAgg = 8 * ((aggBlocks + 3) / 4);      // 25000: 4 XCDs per half

    // --- layer 1 (A = X fp32, split in-kernel) ---
    gemm_mfma<8, 8, true><<<gemmRows, 256, 0, stream>>>(X, nullptr, nullptr,
                                                        B1h, B1l, C16, ssb, dsb, N);
    aggregate_oc<8, false, true><<<gridAgg, 256, 0, stream>>>(
        C16, ssb, dsb, csr, begE, endE, b1, Ph, Pl, nullptr, N, aggBlocks);

    // --- layer 2 (agg writes back over Ph/Pl, dead after gemm2 reads them) ---
    gemm_mfma<8, 8, false><<<gemmRows, 256, 0, stream>>>(nullptr, Ph, Pl,
                                                         B2h, B2l, C16, ssb, dsb, N);
    aggregate_oc<8, false, true><<<gridAgg, 256, 0, stream>>>(
        C16, ssb, dsb, csr, begE, endE, b2, Ph, Pl, nullptr, N, aggBlocks);

    // --- layer 3 (H=4, halves of 2 heads, mean via d_out atomics) ---
    gemm_mfma<4, 4, false><<<gemmRows, 256, 0, stream>>>(nullptr, Ph, Pl,
                                                         B3h, B3l, C16, ssb, dsb, N);
    aggregate_oc<4, true, false><<<gridAgg, 256, 0, stream>>>(
        C16, ssb, dsb, csr, begE, endE, b3, nullptr, nullptr, (float*)d_out, N, aggBlocks);
}